// Round 3
// baseline (27710.867 us; speedup 1.0000x reference)
//
#include <hip/hip_runtime.h>
#include <stdint.h>

typedef unsigned int u32;
typedef __attribute__((ext_vector_type(2))) float f32x2;
typedef __attribute__((ext_vector_type(4))) float f32x4;

static const int kD = 1024;
static const long kOutB = 256*1024;   // per-batch stride in out/input [64,256,1024]

__device__ __forceinline__ float fexp2(float x){ return __builtin_amdgcn_exp2f(x); }
__device__ __forceinline__ float frcp(float x){ return __builtin_amdgcn_rcpf(x); }
__device__ __forceinline__ float tanh_(float x){ float e = fexp2(x*2.885390081777927f); return 1.f - 2.f*frcp(e+1.f); }
__device__ __forceinline__ float sigm_(float x){ return frcp(1.f + fexp2(-1.4426950408889634f*x)); }

// ---- init: h0 = hidden^T, outs[:,0,:] = input[:,0,:] ----
__global__ void k_init(const float* __restrict__ hidden, const float* __restrict__ input,
                       float* __restrict__ h0f, float* __restrict__ out){
    int i = blockIdx.x*blockDim.x + threadIdx.x;   // 65536
    int b = i >> 10, d = i & 1023;
    h0f[i] = hidden[d*64 + b];
    out[(long)b*kOutB + d] = input[(long)b*kOutB + d];
}

// ===== f32 GEMM NN: C[M,N] = A[M,K] @ B[K,N] (ep one-time) =====
// 256 thr, 64x64 tile, BK=128, thread-tile 4x4 (float2 accum)
__global__ __launch_bounds__(256) void k_gemm_nn(const float* __restrict__ A,
                                                 const float* __restrict__ B,
                                                 float* __restrict__ C,
                                                 int M, int N, int K){
    __shared__ float As[128][64];   // [k][m]
    __shared__ float Bs[128][64];   // [k][n]
    int m0 = blockIdx.x*64, n0 = blockIdx.y*64;
    int tid = threadIdx.x, tx = tid & 15, ty = tid >> 4;
    f32x2 acc[2][4] = {};
    for(int k0 = 0; k0 < K; k0 += 128){
        #pragma unroll
        for(int i = 0; i < 8; ++i){
            int flat = tid + i*256;
            int row = flat >> 5, kq = flat & 31;
            f32x4 va = *(const f32x4*)(A + (long)(m0+row)*K + k0 + kq*4);
            As[kq*4+0][row] = va.x; As[kq*4+1][row] = va.y;
            As[kq*4+2][row] = va.z; As[kq*4+3][row] = va.w;
        }
        #pragma unroll
        for(int i = 0; i < 8; ++i){
            int flat = tid + i*256;
            int kk = flat >> 4, nq = flat & 15;
            *(f32x4*)&Bs[kk][nq*4] = *(const f32x4*)(B + (long)(k0+kk)*N + n0 + nq*4);
        }
        __syncthreads();
        #pragma unroll 8
        for(int k = 0; k < 128; ++k){
            f32x4 a = *(const f32x4*)&As[k][ty*4];
            f32x4 b = *(const f32x4*)&Bs[k][tx*4];
            f32x2 a0 = {a.x, a.y}, a1 = {a.z, a.w};
            #pragma unroll
            for(int j = 0; j < 4; ++j){
                f32x2 bb = {b[j], b[j]};
                acc[0][j] += a0*bb;
                acc[1][j] += a1*bb;
            }
        }
        __syncthreads();
    }
    #pragma unroll
    for(int r = 0; r < 4; ++r){
        f32x4 o = { acc[r>>1][0][r&1], acc[r>>1][1][r&1], acc[r>>1][2][r&1], acc[r>>1][3][r&1] };
        *(f32x4*)(C + (long)(m0 + ty*4 + r)*N + n0 + tx*4) = o;
    }
}

// ===== hW partial: C_part[kb][64,1024] = h[64, k-slice] @ W_dec[k-slice, 1024] =====
// grid (16 nb, 8 kb), BK=128
__global__ __launch_bounds__(256) void k_hw_part(const float* __restrict__ h,
                                                 const float* __restrict__ Wd,
                                                 float* __restrict__ hWp){
    __shared__ float As[128][64];
    __shared__ float Bs[128][64];
    int n0 = blockIdx.x*64, k0 = blockIdx.y*128;
    int tid = threadIdx.x, tx = tid & 15, ty = tid >> 4;
    #pragma unroll
    for(int i = 0; i < 8; ++i){
        int flat = tid + i*256;
        int row = flat >> 5, kq = flat & 31;
        f32x4 va = *(const f32x4*)(h + (long)row*1024 + k0 + kq*4);
        As[kq*4+0][row] = va.x; As[kq*4+1][row] = va.y;
        As[kq*4+2][row] = va.z; As[kq*4+3][row] = va.w;
    }
    #pragma unroll
    for(int i = 0; i < 8; ++i){
        int flat = tid + i*256;
        int kk = flat >> 4, nq = flat & 15;
        *(f32x4*)&Bs[kk][nq*4] = *(const f32x4*)(Wd + (long)(k0+kk)*1024 + n0 + nq*4);
    }
    __syncthreads();
    f32x2 acc[2][4] = {};
    #pragma unroll 8
    for(int k = 0; k < 128; ++k){
        f32x4 a = *(const f32x4*)&As[k][ty*4];
        f32x4 b = *(const f32x4*)&Bs[k][tx*4];
        f32x2 a0 = {a.x, a.y}, a1 = {a.z, a.w};
        #pragma unroll
        for(int j = 0; j < 4; ++j){
            f32x2 bb = {b[j], b[j]};
            acc[0][j] += a0*bb;
            acc[1][j] += a1*bb;
        }
    }
    #pragma unroll
    for(int r = 0; r < 4; ++r){
        f32x4 o = { acc[r>>1][0][r&1], acc[r>>1][1][r&1], acc[r>>1][2][r&1], acc[r>>1][3][r&1] };
        *(f32x4*)(hWp + ((long)blockIdx.y*64 + ty*4 + r)*1024 + n0 + tx*4) = o;
    }
}

// ===== energy[b,s] = v . tanh(ep[b,s,:] + hW[b,:]) masked; sums hW partials =====
// grid 256 = (b, s-quarter), 256 thr (4 waves x 16 s)
__global__ __launch_bounds__(256) void k_energy(const float* __restrict__ hWp,
                                                const float* __restrict__ ep,
                                                const float* __restrict__ vv,
                                                const int* __restrict__ lengths,
                                                float* __restrict__ eny){
    __shared__ float sh[1024];
    __shared__ float sv[1024];
    int b = blockIdx.x >> 2, sq = blockIdx.x & 3;
    int tid = threadIdx.x;
    for(int i = tid; i < 1024; i += 256){
        float s = 0.f;
        #pragma unroll
        for(int kb = 0; kb < 8; ++kb) s += hWp[((long)kb*64 + b)*1024 + i];
        sh[i] = s; sv[i] = vv[i];
    }
    __syncthreads();
    int w = tid >> 6, l = tid & 63;
    int len = lengths[b];
    for(int si = 0; si < 16; ++si){
        int s = sq*64 + w*16 + si;
        const float* row = ep + ((long)(b*256 + s))*1024;
        float acc = 0.f;
        #pragma unroll
        for(int j = 0; j < 16; ++j){
            int k = j*64 + l;
            acc += sv[k]*tanh_(row[k] + sh[k]);
        }
        #pragma unroll
        for(int off = 32; off; off >>= 1) acc += __shfl_xor(acc, off);
        if(l == 0) eny[b*256 + s] = (s < len) ? acc : -1e9f;
    }
}

// ===== softmax(energy) + ctx[b, d-quarter] = attn @ enc =====
// grid 256 = (b, d-quarter), 256 thr
__global__ __launch_bounds__(256) void k_ctx(const float* __restrict__ eny,
                                             const float* __restrict__ enc,
                                             float* __restrict__ ctx){
    __shared__ float sp[256];
    __shared__ float red[8];
    int b = blockIdx.x >> 2, dq = blockIdx.x & 3;
    int tid = threadIdx.x;
    float e = eny[b*256 + tid];
    float m = e;
    #pragma unroll
    for(int off = 32; off; off >>= 1) m = fmaxf(m, __shfl_xor(m, off));
    if((tid & 63) == 0) red[tid >> 6] = m;
    __syncthreads();
    m = fmaxf(fmaxf(red[0], red[1]), fmaxf(red[2], red[3]));
    float p = fexp2((e - m)*1.4426950408889634f);
    sp[tid] = p;
    float sm = p;
    #pragma unroll
    for(int off = 32; off; off >>= 1) sm += __shfl_xor(sm, off);
    if((tid & 63) == 0) red[4 + (tid >> 6)] = sm;
    __syncthreads();
    float inv = 1.f / (red[4] + red[5] + red[6] + red[7]);
    int d = dq*256 + tid;
    const float* eb = enc + (long)b*256*1024 + d;
    float acc = 0.f;
    #pragma unroll 4
    for(int s = 0; s < 256; ++s) acc += sp[s]*eb[(long)s*1024];
    ctx[(long)b*1024 + d] = acc*inv;
}

// ===== GRU partial: gp[kb][64,3072] over virtual K=3072 ([sel|ctx] via W_ih, h via W_hh) =====
// grid (48 nb, 24 kb), BK=128
__global__ __launch_bounds__(256) void k_gru_part(const float* __restrict__ sel, long sstr,
                                                  const float* __restrict__ ctx,
                                                  const float* __restrict__ h,
                                                  const float* __restrict__ Wih,
                                                  const float* __restrict__ Whh,
                                                  float* __restrict__ gp){
    __shared__ float As[128][64];
    __shared__ float Bs[128][64];
    int n0 = blockIdx.x*64, k0 = blockIdx.y*128;
    int tid = threadIdx.x, tx = tid & 15, ty = tid >> 4;
    const float* Aseg; long astr; int koff;
    if(k0 < 1024){ Aseg = sel; astr = sstr; koff = k0; }
    else if(k0 < 2048){ Aseg = ctx; astr = 1024; koff = k0 - 1024; }
    else { Aseg = h; astr = 1024; koff = k0 - 2048; }
    #pragma unroll
    for(int i = 0; i < 8; ++i){
        int flat = tid + i*256;
        int row = flat >> 5, kq = flat & 31;
        f32x4 va = *(const f32x4*)(Aseg + (long)row*astr + koff + kq*4);
        As[kq*4+0][row] = va.x; As[kq*4+1][row] = va.y;
        As[kq*4+2][row] = va.z; As[kq*4+3][row] = va.w;
    }
    #pragma unroll
    for(int i = 0; i < 8; ++i){
        int flat = tid + i*256;
        int row = flat >> 5, kq = flat & 31;
        const float* bp = (k0 < 2048) ? (Wih + (long)(n0+row)*2048 + k0 + kq*4)
                                      : (Whh + (long)(n0+row)*1024 + (k0-2048) + kq*4);
        f32x4 vb = *(const f32x4*)bp;
        Bs[kq*4+0][row] = vb.x; Bs[kq*4+1][row] = vb.y;
        Bs[kq*4+2][row] = vb.z; Bs[kq*4+3][row] = vb.w;
    }
    __syncthreads();
    f32x2 acc[2][4] = {};
    #pragma unroll 8
    for(int k = 0; k < 128; ++k){
        f32x4 a = *(const f32x4*)&As[k][ty*4];
        f32x4 b = *(const f32x4*)&Bs[k][tx*4];
        f32x2 a0 = {a.x, a.y}, a1 = {a.z, a.w};
        #pragma unroll
        for(int j = 0; j < 4; ++j){
            f32x2 bb = {b[j], b[j]};
            acc[0][j] += a0*bb;
            acc[1][j] += a1*bb;
        }
    }
    #pragma unroll
    for(int r = 0; r < 4; ++r){
        f32x4 o = { acc[r>>1][0][r&1], acc[r>>1][1][r&1], acc[r>>1][2][r&1], acc[r>>1][3][r&1] };
        *(f32x4*)(gp + ((long)blockIdx.y*64 + ty*4 + r)*3072 + n0 + tx*4) = o;
    }
}

// ===== GRU finalize: reduce 24 partials, gates, h_new, out =====
// grid 256 = (b, u-quarter), 256 thr; kb<16 = x-part (gi), kb>=16 = h-part (gh)
__global__ __launch_bounds__(256) void k_gru_fin(const float* __restrict__ gp,
                                                 const float* __restrict__ bih,
                                                 const float* __restrict__ bhh,
                                                 const float* __restrict__ hf_old,
                                                 float* __restrict__ hf_new,
                                                 float* __restrict__ outp){
    int b = blockIdx.x >> 2, uq = blockIdx.x & 3;
    int u = uq*256 + threadIdx.x;
    float sr = 0.f, sz = 0.f, sxn = 0.f, shn = 0.f;
    #pragma unroll
    for(int kb = 0; kb < 24; ++kb){
        const float* base = gp + ((long)kb*64 + b)*3072;
        sr += base[u];
        sz += base[1024 + u];
        float pn = base[2048 + u];
        if(kb < 16) sxn += pn; else shn += pn;
    }
    float rg = sigm_(sr + bih[u] + bhh[u]);
    float z  = sigm_(sz + bih[1024+u] + bhh[1024+u]);
    float n  = tanh_(sxn + bih[2048+u] + rg*(shn + bhh[2048+u]));
    float hold = hf_old[(long)b*1024 + u];
    float hn = (1.f - z)*n + z*hold;
    hf_new[(long)b*1024 + u] = hn;
    outp[(long)b*kOutB + u] = hn;
}

// ---- host: JAX Threefry-2x32 core (verified vs Random123 KAT) ----
static inline u32 rotl32(u32 x, int r){ return (x << r) | (x >> (32 - r)); }
static void threefry_pair(u32 x0, u32 x1, u32 k0, u32 k1, u32* o0, u32* o1){
    const u32 ks0 = k0, ks1 = k1, ks2 = k0 ^ k1 ^ 0x1BD11BDAu;
    static const int R0[4] = {13,15,26,6}, R1[4] = {17,29,16,24};
    x0 += ks0; x1 += ks1;
    for(int i=0;i<4;i++){ x0 += x1; x1 = rotl32(x1,R0[i]); x1 ^= x0; }
    x0 += ks1; x1 += ks2 + 1u;
    for(int i=0;i<4;i++){ x0 += x1; x1 = rotl32(x1,R1[i]); x1 ^= x0; }
    x0 += ks2; x1 += ks0 + 2u;
    for(int i=0;i<4;i++){ x0 += x1; x1 = rotl32(x1,R0[i]); x1 ^= x0; }
    x0 += ks0; x1 += ks1 + 3u;
    for(int i=0;i<4;i++){ x0 += x1; x1 = rotl32(x1,R1[i]); x1 ^= x0; }
    x0 += ks1; x1 += ks2 + 4u;
    for(int i=0;i<4;i++){ x0 += x1; x1 = rotl32(x1,R0[i]); x1 ^= x0; }
    x0 += ks2; x1 += ks0 + 5u;
    *o0 = x0; *o1 = x1;
}

extern "C" void kernel_launch(void* const* d_in, const int* in_sizes, int n_in,
                              void* d_out, int out_size, void* d_ws, size_t ws_size,
                              hipStream_t stream){
    (void)in_sizes; (void)n_in; (void)out_size;
    const float* input    = (const float*)d_in[0];   // [64,256,1024]
    const float* hidden   = (const float*)d_in[1];   // [1024,64]
    const float* enc_outs = (const float*)d_in[2];   // [64,256,1024]
    const int*   lengths  = (const int*)  d_in[3];   // [64]
    const float* W_enc    = (const float*)d_in[4];   // [1024,1024] (K,N)
    const float* W_dec    = (const float*)d_in[5];   // [1024,1024] (K,N)
    const float* v        = (const float*)d_in[6];   // [1024]
    const float* W_ih     = (const float*)d_in[7];   // [3072,2048] (N,K)
    const float* W_hh     = (const float*)d_in[8];   // [3072,1024] (N,K)
    const float* b_ih     = (const float*)d_in[9];
    const float* b_hh     = (const float*)d_in[10];
    float* out = (float*)d_out;                      // [64,256,1024]

    // ---- workspace carve (~87 MB), all f32 ----
    char* p = (char*)d_ws;
    auto alloc = [&](size_t bytes){ void* r = (void*)p; p += (bytes + 255) & ~(size_t)255; return r; };
    float* ep   = (float*)alloc((size_t)16384*1024*4);    // enc_proj f32
    float* hWp  = (float*)alloc((size_t)8*64*1024*4);     // hW K-split partials
    float* eny  = (float*)alloc((size_t)64*256*4);
    float* ctxf = (float*)alloc((size_t)64*1024*4);
    float* gp   = (float*)alloc((size_t)24*64*3072*4);    // GRU K-split partials
    float* hf0  = (float*)alloc((size_t)64*1024*4);
    float* hf1  = (float*)alloc((size_t)64*1024*4);
    if((size_t)(p - (char*)d_ws) > ws_size) return;       // insufficient scratch

    // ---- teacher-forcing flags: MODERN JAX (jax_threefry_partitionable=True).
    // Element j: counter64 = j -> (hi,lo) = (0,j); bits32 = o0 ^ o1;
    // uniform(bits) < 0.5  <=>  bit31(bits) == 0.  Key = PRNGKey(1) = (0,1).
    bool tf[255];
    for(int j = 0; j < 255; ++j){
        u32 o0, o1;
        threefry_pair(0u, (u32)j, 0u, 1u, &o0, &o1);
        tf[j] = (((o0 ^ o1) >> 31) == 0u);
    }

    // ---- one-time prep ----
    k_init<<<256, 256, 0, stream>>>(hidden, input, hf0, out);
    k_gemm_nn<<<dim3(256,16), 256, 0, stream>>>(enc_outs, W_enc, ep, 16384, 1024, 1024);

    // ---- 255 sequential steps ----
    float* hf[2] = {hf0, hf1};
    for(int t = 1; t < 256; ++t){
        int pp = (t - 1) & 1, q = t & 1;
        k_hw_part<<<dim3(16,8), 256, 0, stream>>>(hf[pp], W_dec, hWp);
        k_energy<<<256, 256, 0, stream>>>(hWp, ep, v, lengths, eny);
        k_ctx<<<256, 256, 0, stream>>>(eny, enc_outs, ctxf);
        bool useTeach = (t == 1) || tf[t - 1];
        const float* selp = useTeach ? (input + (long)(t - 1)*1024) : hf[pp];
        long sstr = useTeach ? kOutB : (long)1024;
        k_gru_part<<<dim3(48,24), 256, 0, stream>>>(selp, sstr, ctxf, hf[pp],
                                                    W_ih, W_hh, gp);
        k_gru_fin<<<256, 256, 0, stream>>>(gp, b_ih, b_hh, hf[pp], hf[q],
                                           out + (long)t*kD);
    }
}

// Round 6
// 20181.244 us; speedup vs baseline: 1.3731x; 1.3731x over previous
//
#include <hip/hip_runtime.h>
#include <stdint.h>

typedef unsigned short u16;
typedef unsigned int   u32;
typedef __attribute__((ext_vector_type(8))) short short8;
typedef __attribute__((ext_vector_type(4))) short s16x4;
typedef __attribute__((ext_vector_type(4))) float f32x4;

#define MFMA(a,b,c) __builtin_amdgcn_mfma_f32_16x16x32_bf16((a),(b),(c),0,0,0)

static const int kD = 1024;
static const long kOutB = 256*1024;   // per-batch stride in out/input [64,256,1024]

__device__ __forceinline__ float b2f(u16 v){ union{u32 u; float f;} c; c.u = ((u32)v)<<16; return c.f; }
__device__ __forceinline__ u16 f2b(float f){ union{float f; u32 u;} c; c.f = f; u32 r = c.u + 0x7FFFu + ((c.u>>16)&1u); return (u16)(r>>16); }
__device__ __forceinline__ float fexp2(float x){ return __builtin_amdgcn_exp2f(x); }
__device__ __forceinline__ float frcp(float x){ return __builtin_amdgcn_rcpf(x); }
__device__ __forceinline__ float tanh_(float x){ float e = fexp2(x*2.885390081777927f); return 1.f - 2.f*frcp(e+1.f); }
__device__ __forceinline__ float sigm_(float x){ return frcp(1.f + fexp2(-1.4426950408889634f*x)); }

// ---- f32 -> bf16 convert (grid-stride) ----
__global__ void k_cvt(const float* __restrict__ in, u16* __restrict__ out, int n){
    int i = blockIdx.x*blockDim.x + threadIdx.x;
    int st = gridDim.x*blockDim.x;
    for(; i < n; i += st) out[i] = f2b(in[i]);
}

// ---- transpose + convert: in [R][C] f32 -> out [C][R] bf16 ----
__global__ void k_cvt_t(const float* __restrict__ in, u16* __restrict__ out, int R, int C){
    __shared__ float tile[32][33];
    int bx = blockIdx.x, by = blockIdx.y;
    int tx = threadIdx.x, ty = threadIdx.y;   // 32 x 8
    for(int j = 0; j < 32; j += 8) tile[ty+j][tx] = in[(by*32+ty+j)*C + bx*32+tx];
    __syncthreads();
    for(int j = 0; j < 32; j += 8) out[(bx*32+ty+j)*R + by*32+tx] = f2b(tile[tx][ty+j]);
}

// ---- init: h0 (f32 + bf16) from hidden^T; outs[:,0,:] = input[:,0,:] (exact f32 copy) ----
__global__ void k_init(const float* __restrict__ hidden, const float* __restrict__ input,
                       float* __restrict__ h0f, u16* __restrict__ h0b, float* __restrict__ out){
    int i = blockIdx.x*blockDim.x + threadIdx.x;   // 65536
    int b = i >> 10, d = i & 1023;
    float h = hidden[d*64 + b];
    h0f[i] = h; h0b[i] = f2b(h);
    out[(long)b*kOutB + d] = input[(long)b*kOutB + d];
}

// ---- enc_proj = encb [16384,1024] @ wencT (N,K) -> epb bf16 ----
__global__ __launch_bounds__(256) void k_gemm_ep(const u16* __restrict__ A, const u16* __restrict__ BT,
                                                 u16* __restrict__ Cb){
    int m0 = blockIdx.x*64, n0 = blockIdx.y*64;
    int w = threadIdx.x >> 6, l = threadIdx.x & 63;
    int r0 = l & 15, kh = (l >> 4) * 8;
    const u16* arow = A + (long)(m0 + w*16 + r0)*1024 + kh;
    f32x4 acc[4] = {};
    for(int k0 = 0; k0 < 1024; k0 += 32){
        short8 a = *(const short8*)(arow + k0);
        #pragma unroll
        for(int j = 0; j < 4; ++j){
            short8 b = *(const short8*)(BT + (long)(n0 + j*16 + r0)*1024 + k0 + kh);
            acc[j] = MFMA(a, b, acc[j]);
        }
    }
    int orow = m0 + w*16 + (l>>4)*4;
    int ocol = n0 + (l & 15);
    #pragma unroll
    for(int j = 0; j < 4; ++j)
        #pragma unroll
        for(int r = 0; r < 4; ++r)
            Cb[(long)(orow + r)*1024 + ocol + j*16] = f2b(acc[j][r]);
}

// ---- hW = hb [64,1024] @ wdecT (N,K) -> f32 [64,1024] ----
__global__ __launch_bounds__(256) void k_hw(const u16* __restrict__ hb, const u16* __restrict__ WdT,
                                            float* __restrict__ hW){
    int n0 = blockIdx.x*16;
    int w = threadIdx.x >> 6, l = threadIdx.x & 63;
    int r0 = l & 15, kh = (l >> 4) * 8;
    const u16* arow = hb  + (w*16 + r0)*1024 + kh;
    const u16* brow = WdT + (n0   + r0)*1024 + kh;
    f32x4 acc = {};
    for(int k0 = 0; k0 < 1024; k0 += 32){
        short8 a = *(const short8*)(arow + k0);
        short8 b = *(const short8*)(brow + k0);
        acc = MFMA(a, b, acc);
    }
    int row = w*16 + (l>>4)*4, col = n0 + (l & 15);
    #pragma unroll
    for(int r = 0; r < 4; ++r) hW[(row + r)*1024 + col] = acc[r];
}

// ---- energy[b,s] = v . tanh(epb[b,s,:] + hW[b,:]), masked ----
// grid 256 = (b, s-quarter), 256 thr (4 waves x 16 s-rows); hW/v cached in regs per lane
__global__ __launch_bounds__(256) void k_energy(const u16* __restrict__ epb, const float* __restrict__ hW,
                                                const float* __restrict__ vv, const int* __restrict__ lengths,
                                                float* __restrict__ eny){
    __shared__ float sh[1024];
    __shared__ float sv[1024];
    int b = blockIdx.x >> 2, sq = blockIdx.x & 3;
    int tid = threadIdx.x;
    for(int i = tid; i < 1024; i += 256){ sh[i] = hW[b*1024 + i]; sv[i] = vv[i]; }
    __syncthreads();
    int w = tid >> 6, l = tid & 63;
    // per-lane register copy of its 16-element slice (one-time LDS reads)
    float rh[16], rv[16];
    #pragma unroll
    for(int j = 0; j < 16; ++j){ rh[j] = sh[l*16 + j]; rv[j] = sv[l*16 + j]; }
    int len = lengths[b];
    int sbase = sq*64 + w*16;
    for(int si = 0; si < 16; ++si){
        int s = sbase + si;
        const u16* row = epb + ((long)(b*256 + s))*1024 + l*16;
        short8 p0 = *(const short8*)(row);
        short8 p1 = *(const short8*)(row + 8);
        float acc = 0.f;
        #pragma unroll
        for(int j = 0; j < 8; ++j) acc += rv[j]   * tanh_(b2f((u16)p0[j]) + rh[j]);
        #pragma unroll
        for(int j = 0; j < 8; ++j) acc += rv[8+j] * tanh_(b2f((u16)p1[j]) + rh[8+j]);
        #pragma unroll
        for(int off = 32; off; off >>= 1) acc += __shfl_xor(acc, off);
        if(l == 0) eny[b*256 + s] = (s < len) ? acc : -1e9f;
    }
}

// ---- softmax + ctx: grid 256 = (b, d-quarter), 256 thr; wave w sums its s-quarter ----
__global__ __launch_bounds__(256) void k_ctx(const float* __restrict__ eny, const u16* __restrict__ encb,
                                             u16* __restrict__ ctxb){
    __shared__ float sp[256];
    __shared__ float red[8];
    __shared__ float part[4][256];
    int b = blockIdx.x >> 2, dq = blockIdx.x & 3;
    int tid = threadIdx.x;
    float e = eny[b*256 + tid];
    float m = e;
    #pragma unroll
    for(int off = 32; off; off >>= 1) m = fmaxf(m, __shfl_xor(m, off));
    if((tid & 63) == 0) red[tid >> 6] = m;
    __syncthreads();
    m = fmaxf(fmaxf(red[0], red[1]), fmaxf(red[2], red[3]));
    float p = fexp2((e - m)*1.4426950408889634f);
    sp[tid] = p;
    float sm = p;
    #pragma unroll
    for(int off = 32; off; off >>= 1) sm += __shfl_xor(sm, off);
    if((tid & 63) == 0) red[4 + (tid >> 6)] = sm;
    __syncthreads();
    float inv = 1.f / (red[4] + red[5] + red[6] + red[7]);
    int w = tid >> 6, l = tid & 63;
    int d0 = dq*256 + l*4;
    const u16* eb = encb + (long)b*256*1024 + d0;
    float a0=0.f, a1=0.f, a2=0.f, a3=0.f;
    #pragma unroll 4
    for(int si = 0; si < 64; ++si){
        int s = w*64 + si;
        float ps = sp[s];
        s16x4 q = *(const s16x4*)(eb + (long)s*1024);
        a0 += ps*b2f((u16)q[0]); a1 += ps*b2f((u16)q[1]);
        a2 += ps*b2f((u16)q[2]); a3 += ps*b2f((u16)q[3]);
    }
    part[w][l*4+0] = a0; part[w][l*4+1] = a1; part[w][l*4+2] = a2; part[w][l*4+3] = a3;
    __syncthreads();
    float c = (part[0][tid] + part[1][tid] + part[2][tid] + part[3][tid]) * inv;
    ctxb[b*1024 + dq*256 + tid] = f2b(c);
}

// ---- fused GRU: gi = [sel|ctx]@W_ih^T, gh = h@W_hh^T, gates -> h_new (f32+bf16), out ----
// 64 blocks (16 gate-cols each) x 256 thr (wave = 16 batch rows)
__global__ __launch_bounds__(256) void k_gru(const u16* __restrict__ selp, long sel_stride,
                                             const u16* __restrict__ ctx, const u16* __restrict__ hb,
                                             const u16* __restrict__ Wih, const u16* __restrict__ Whh,
                                             const float* __restrict__ bih, const float* __restrict__ bhh,
                                             const float* __restrict__ hf_old, float* __restrict__ hf_new,
                                             u16* __restrict__ hb_new, float* __restrict__ outp){
    int u0 = blockIdx.x*16;
    int w = threadIdx.x >> 6, l = threadIdx.x & 63;
    int r0 = l & 15, kh = (l >> 4) * 8;
    f32x4 air = {}, aiz = {}, ain = {}, ahr = {}, ahz = {}, ahn = {};
    const u16* selrow = selp + (long)(w*16 + r0)*sel_stride + kh;
    const u16* ctxrow = ctx  + (w*16 + r0)*1024 + kh;
    const u16* hrow   = hb   + (w*16 + r0)*1024 + kh;
    const u16* wr = Wih + (long)(       u0 + r0)*2048 + kh;
    const u16* wz = Wih + (long)(1024 + u0 + r0)*2048 + kh;
    const u16* wn = Wih + (long)(2048 + u0 + r0)*2048 + kh;
    const u16* vr = Whh + (long)(       u0 + r0)*1024 + kh;
    const u16* vz = Whh + (long)(1024 + u0 + r0)*1024 + kh;
    const u16* vn = Whh + (long)(2048 + u0 + r0)*1024 + kh;
    for(int k0 = 0; k0 < 1024; k0 += 32){
        short8 a = *(const short8*)(selrow + k0);
        air = MFMA(a, *(const short8*)(wr + k0), air);
        aiz = MFMA(a, *(const short8*)(wz + k0), aiz);
        ain = MFMA(a, *(const short8*)(wn + k0), ain);
        short8 h = *(const short8*)(hrow + k0);
        ahr = MFMA(h, *(const short8*)(vr + k0), ahr);
        ahz = MFMA(h, *(const short8*)(vz + k0), ahz);
        ahn = MFMA(h, *(const short8*)(vn + k0), ahn);
    }
    for(int k0 = 0; k0 < 1024; k0 += 32){
        short8 a = *(const short8*)(ctxrow + k0);
        air = MFMA(a, *(const short8*)(wr + 1024 + k0), air);
        aiz = MFMA(a, *(const short8*)(wz + 1024 + k0), aiz);
        ain = MFMA(a, *(const short8*)(wn + 1024 + k0), ain);
    }
    int row = w*16 + (l>>4)*4;
    int u = u0 + (l & 15);
    float bir = bih[u], biz = bih[1024+u], bin_ = bih[2048+u];
    float bhr = bhh[u], bhz = bhh[1024+u], bhn  = bhh[2048+u];
    #pragma unroll
    for(int r = 0; r < 4; ++r){
        int b = row + r;
        float rg = sigm_(air[r] + bir + ahr[r] + bhr);
        float z  = sigm_(aiz[r] + biz + ahz[r] + bhz);
        float n  = tanh_(ain[r] + bin_ + rg*(ahn[r] + bhn));
        float hold = hf_old[b*1024 + u];
        float hn = (1.f - z)*n + z*hold;
        hf_new[b*1024 + u] = hn;
        hb_new[b*1024 + u] = f2b(hn);
        outp[(long)b*kOutB + u] = hn;
    }
}

// ---- host: JAX Threefry-2x32 core ----
static inline u32 rotl32(u32 x, int r){ return (x << r) | (x >> (32 - r)); }
static void threefry_pair(u32 x0, u32 x1, u32 k0, u32 k1, u32* o0, u32* o1){
    const u32 ks0 = k0, ks1 = k1, ks2 = k0 ^ k1 ^ 0x1BD11BDAu;
    static const int R0[4] = {13,15,26,6}, R1[4] = {17,29,16,24};
    x0 += ks0; x1 += ks1;
    for(int i=0;i<4;i++){ x0 += x1; x1 = rotl32(x1,R0[i]); x1 ^= x0; }
    x0 += ks1; x1 += ks2 + 1u;
    for(int i=0;i<4;i++){ x0 += x1; x1 = rotl32(x1,R1[i]); x1 ^= x0; }
    x0 += ks2; x1 += ks0 + 2u;
    for(int i=0;i<4;i++){ x0 += x1; x1 = rotl32(x1,R0[i]); x1 ^= x0; }
    x0 += ks0; x1 += ks1 + 3u;
    for(int i=0;i<4;i++){ x0 += x1; x1 = rotl32(x1,R1[i]); x1 ^= x0; }
    x0 += ks1; x1 += ks2 + 4u;
    for(int i=0;i<4;i++){ x0 += x1; x1 = rotl32(x1,R0[i]); x1 ^= x0; }
    x0 += ks2; x1 += ks0 + 5u;
    *o0 = x0; *o1 = x1;
}

extern "C" void kernel_launch(void* const* d_in, const int* in_sizes, int n_in,
                              void* d_out, int out_size, void* d_ws, size_t ws_size,
                              hipStream_t stream){
    (void)in_sizes; (void)n_in; (void)out_size;
    const float* input    = (const float*)d_in[0];   // [64,256,1024]
    const float* hidden   = (const float*)d_in[1];   // [1024,64]
    const float* enc_outs = (const float*)d_in[2];   // [64,256,1024]
    const int*   lengths  = (const int*)  d_in[3];   // [64]
    const float* W_enc    = (const float*)d_in[4];   // [1024,1024] (K,N)
    const float* W_dec    = (const float*)d_in[5];   // [1024,1024] (K,N)
    const float* v        = (const float*)d_in[6];   // [1024]
    const float* W_ih     = (const float*)d_in[7];   // [3072,2048] (N,K)
    const float* W_hh     = (const float*)d_in[8];   // [3072,1024] (N,K)
    const float* b_ih     = (const float*)d_in[9];
    const float* b_hh     = (const float*)d_in[10];
    float* out = (float*)d_out;                      // [64,256,1024]

    // ---- workspace carve (~117 MB) ----
    char* p = (char*)d_ws;
    auto alloc = [&](size_t bytes){ void* r = (void*)p; p += (bytes + 255) & ~(size_t)255; return r; };
    u16* epb   = (u16*)alloc((size_t)16384*1024*2);   // enc_proj bf16
    u16* inb   = (u16*)alloc((size_t)16384*1024*2);   // input bf16
    u16* encb  = (u16*)alloc((size_t)16384*1024*2);   // encoder_outs bf16
    u16* wihb  = (u16*)alloc((size_t)3072*2048*2);
    u16* whhb  = (u16*)alloc((size_t)3072*1024*2);
    u16* wencT = (u16*)alloc((size_t)1024*1024*2);
    u16* wdecT = (u16*)alloc((size_t)1024*1024*2);
    float* hf0 = (float*)alloc((size_t)64*1024*4);
    float* hf1 = (float*)alloc((size_t)64*1024*4);
    u16* hb0   = (u16*)alloc((size_t)64*1024*2);
    u16* hb1   = (u16*)alloc((size_t)64*1024*2);
    float* hW  = (float*)alloc((size_t)64*1024*4);
    float* eny = (float*)alloc((size_t)64*256*4);
    u16* ctxb  = (u16*)alloc((size_t)64*1024*2);
    if((size_t)(p - (char*)d_ws) > ws_size) return;

    // ---- teacher-forcing flags: modern JAX partitionable threefry, key(1)=(0,1) ----
    // element j: counter (hi,lo)=(0,j); bits = o0 ^ o1; u<0.5 <=> bit31==0
    bool tf[255];
    for(int j = 0; j < 255; ++j){
        u32 o0, o1;
        threefry_pair(0u, (u32)j, 0u, 1u, &o0, &o1);
        tf[j] = (((o0 ^ o1) >> 31) == 0u);
    }

    // ---- one-time prep ----
    k_cvt<<<2048, 256, 0, stream>>>(enc_outs, encb, 16384*1024);
    k_cvt<<<2048, 256, 0, stream>>>(input,    inb,  16384*1024);
    k_cvt<<<1024, 256, 0, stream>>>(W_ih,     wihb, 3072*2048);
    k_cvt<<<512,  256, 0, stream>>>(W_hh,     whhb, 3072*1024);
    k_cvt_t<<<dim3(32,32), dim3(32,8), 0, stream>>>(W_enc, wencT, 1024, 1024);
    k_cvt_t<<<dim3(32,32), dim3(32,8), 0, stream>>>(W_dec, wdecT, 1024, 1024);
    k_init<<<256, 256, 0, stream>>>(hidden, input, hf0, hb0, out);
    k_gemm_ep<<<dim3(256,16), 256, 0, stream>>>(encb, wencT, epb);

    // ---- 255 sequential steps ----
    float* hf[2] = {hf0, hf1};
    u16*   hbb[2] = {hb0, hb1};
    for(int t = 1; t < 256; ++t){
        int pp = (t - 1) & 1, q = t & 1;
        k_hw<<<64, 256, 0, stream>>>(hbb[pp], wdecT, hW);
        k_energy<<<256, 256, 0, stream>>>(epb, hW, v, lengths, eny);
        k_ctx<<<256, 256, 0, stream>>>(eny, encb, ctxb);
        bool useTeach = (t == 1) || tf[t - 1];
        const u16* selp = useTeach ? (inb + (long)(t - 1)*1024) : hbb[pp];
        long sstr = useTeach ? kOutB : (long)kD;
        k_gru<<<64, 256, 0, stream>>>(selp, sstr, ctxb, hbb[pp], wihb, whhb,
                                      b_ih, b_hh, hf[pp], hf[q], hbb[q],
                                      out + (long)t*kD);
    }
}